// Round 3
// baseline (1685.935 us; speedup 1.0000x reference)
//
#include <hip/hip_runtime.h>

typedef unsigned int   uint32;
typedef unsigned short ushort16;

#define NN     50000
#define RR     16
#define BB     8
#define DIN    128
#define DOUT   128
#define NNZ_C  1600000
#define NBLK   782                 // ceil(NN/64)
#define NKEY   (NBLK * 16)         // 12512 buckets
#define NB2    49                  // ceil(NKEY/256)

#define YF_STRIDE 132              // 128 + 4 pad (f32 words)
#define WT_STRIDE 136              // 128 + 8 pad (bf16 elems)

typedef short  short8  __attribute__((ext_vector_type(8)));
typedef float  floatx4 __attribute__((ext_vector_type(4)));

__device__ __forceinline__ ushort16 f2bf(float f) {
    uint32 u = __float_as_uint(f);
    u += 0x7fffu + ((u >> 16) & 1u);   // RNE
    return (ushort16)(u >> 16);
}

// pack two f32 -> (bf16(b)<<16)|bf16(a), round-half-up, 3 VALU ops
__device__ __forceinline__ uint32 pack_bf16(float a, float b) {
    uint32 ua = __float_as_uint(a) + 0x8000u;
    uint32 ub = __float_as_uint(b) + 0x8000u;
    // v_perm: sel idx 0-3 from src1(ua), 4-7 from src0(ub)
    return __builtin_amdgcn_perm(ub, ua, 0x07060302);
}

// ---------------------------------------------------------------------------
// Wt[r][j][k] = sum_b comp[r][b] * basis[b][k][j]   (bf16, k-contiguous)
// ---------------------------------------------------------------------------
__global__ void build_wt_kernel(const float* __restrict__ basis,
                                const float* __restrict__ comp,
                                ushort16* __restrict__ Wt) {
    int idx = blockIdx.x * 256 + threadIdx.x;      // R*DOUT*DIN = 262144
    int r = idx >> 14;
    int j = (idx >> 7) & 127;
    int k = idx & 127;
    float s = 0.f;
#pragma unroll
    for (int b = 0; b < BB; ++b)
        s += comp[r * BB + b] * basis[((size_t)b * DIN + k) * DOUT + j];
    Wt[idx] = f2bf(s);
}

// ---------------------------------------------------------------------------
// CSR build over keys (row>>6)*16 + r,  r = col / NN
// ---------------------------------------------------------------------------
__global__ void hist_kernel(const int* __restrict__ rows,
                            const int* __restrict__ cols,
                            int* __restrict__ counts) {
    int e = blockIdx.x * 256 + threadIdx.x;
    int row = rows[e];
    int r   = cols[e] / NN;
    atomicAdd(&counts[(row >> 6) * 16 + r], 1);
}

__global__ void scan1_kernel(const int* __restrict__ counts,
                             int* __restrict__ row_start,
                             int* __restrict__ block_sums) {
    __shared__ int tmp[256];
    int tid = threadIdx.x;
    int gid = blockIdx.x * 256 + tid;
    int v = (gid < NKEY) ? counts[gid] : 0;
    tmp[tid] = v;
    __syncthreads();
#pragma unroll
    for (int off = 1; off < 256; off <<= 1) {
        int t = (tid >= off) ? tmp[tid - off] : 0;
        __syncthreads();
        tmp[tid] += t;
        __syncthreads();
    }
    if (gid < NKEY) row_start[gid] = tmp[tid] - v;     // exclusive
    if (tid == 255) block_sums[blockIdx.x] = tmp[255];
}

__global__ void scan2_kernel(const int* __restrict__ block_sums,
                             int* __restrict__ block_offs) {
    __shared__ int tmp[256];
    int tid = threadIdx.x;
    int v = (tid < NB2) ? block_sums[tid] : 0;
    tmp[tid] = v;
    __syncthreads();
#pragma unroll
    for (int off = 1; off < 256; off <<= 1) {
        int t = (tid >= off) ? tmp[tid - off] : 0;
        __syncthreads();
        tmp[tid] += t;
        __syncthreads();
    }
    if (tid < NB2) block_offs[tid] = tmp[tid] - v;     // exclusive
}

__global__ void scan3_kernel(int* __restrict__ row_start,
                             const int* __restrict__ block_offs) {
    int gid = blockIdx.x * 256 + threadIdx.x;
    if (gid < NKEY) row_start[gid] += block_offs[blockIdx.x];
}

// bucket: es[pos] = { col_local | (row_local<<16), val_bits }
// uses row_start itself as cursor; afterwards row_start[key] == end(key)
__global__ void bucket_kernel(const int* __restrict__ rows,
                              const int* __restrict__ cols,
                              const float* __restrict__ vals,
                              int* __restrict__ row_start,
                              uint2* __restrict__ es) {
    int e = blockIdx.x * 256 + threadIdx.x;
    int row = rows[e];
    int col = cols[e];
    int r   = col / NN;
    int cl  = col - r * NN;                 // < 50000, fits 16 bits
    int key = (row >> 6) * 16 + r;
    int pos = atomicAdd(&row_start[key], 1);
    es[pos] = make_uint2((uint32)cl | ((uint32)(row & 63) << 16),
                         __float_as_uint(vals[e]));
}

// ---------------------------------------------------------------------------
// Fused: per block (64 output rows), loop r: Y = A_r-slice gather of X (LDS,
// f32 atomics) -> bf16 -> MFMA with Wt[r] -> accumulate out in regs.
// ---------------------------------------------------------------------------
__global__ __launch_bounds__(256) void fused_spmm_kernel(
        const uint2* __restrict__ es,
        const int*   __restrict__ row_start,
        const float* __restrict__ X,
        const ushort16* __restrict__ Wt,
        float* __restrict__ out) {
    __shared__ __align__(16) float    Yf[64 * YF_STRIDE];        // 33792 B
    __shared__ __align__(16) ushort16 Wt_lds[128 * WT_STRIDE];   // 34816 B

    const int tid  = threadIdx.x;
    const int wave = tid >> 6;
    const int lane = tid & 63;
    const int m    = lane & 15;
    const int half = lane >> 4;
    const int blk  = blockIdx.x;

    floatx4 acc[8] = {};

    for (int r = 0; r < RR; ++r) {
        __syncthreads();   // previous iteration's LDS readers done

        // zero Yf[64][0..128): 8 x float4 per thread
        {
            int zr = tid >> 2;
            int zc = (tid & 3) * 32;
            float4 z = make_float4(0.f, 0.f, 0.f, 0.f);
#pragma unroll
            for (int i = 0; i < 8; ++i)
                *(float4*)&Yf[zr * YF_STRIDE + zc + i * 4] = z;
        }
        // stage Wt[r] into LDS (32 KB), 8 x 16B per thread
        {
            const uint4* wt_g = (const uint4*)(Wt + (size_t)r * DOUT * DIN);
#pragma unroll
            for (int it = 0; it < 8; ++it) {
                int g8 = (it * 256 + tid) * 8;
                int j  = g8 >> 7;
                int k  = g8 & 127;
                *(uint4*)&Wt_lds[j * WT_STRIDE + k] = wt_g[g8 >> 3];
            }
        }
        __syncthreads();

        // gather phase: edges of bucket (blk, r); lane covers cols {lane, lane+64}
        int key = blk * 16 + r;
        int beg = (key == 0) ? 0 : row_start[key - 1];
        int end = row_start[key];
        int e = beg + wave;
        for (; e + 12 < end; e += 16) {        // 4 edges in flight per wave
            uint2 p0 = es[e];
            uint2 p1 = es[e + 4];
            uint2 p2 = es[e + 8];
            uint2 p3 = es[e + 12];
            int c0 = p0.x & 0xffff, rl0 = p0.x >> 16;
            int c1 = p1.x & 0xffff, rl1 = p1.x >> 16;
            int c2 = p2.x & 0xffff, rl2 = p2.x >> 16;
            int c3 = p3.x & 0xffff, rl3 = p3.x >> 16;
            float v0 = __uint_as_float(p0.y), v1 = __uint_as_float(p1.y);
            float v2 = __uint_as_float(p2.y), v3 = __uint_as_float(p3.y);
            float xa0 = X[(c0 << 7) + lane], xb0 = X[(c0 << 7) + 64 + lane];
            float xa1 = X[(c1 << 7) + lane], xb1 = X[(c1 << 7) + 64 + lane];
            float xa2 = X[(c2 << 7) + lane], xb2 = X[(c2 << 7) + 64 + lane];
            float xa3 = X[(c3 << 7) + lane], xb3 = X[(c3 << 7) + 64 + lane];
            atomicAdd(&Yf[rl0 * YF_STRIDE + lane],      v0 * xa0);
            atomicAdd(&Yf[rl0 * YF_STRIDE + 64 + lane], v0 * xb0);
            atomicAdd(&Yf[rl1 * YF_STRIDE + lane],      v1 * xa1);
            atomicAdd(&Yf[rl1 * YF_STRIDE + 64 + lane], v1 * xb1);
            atomicAdd(&Yf[rl2 * YF_STRIDE + lane],      v2 * xa2);
            atomicAdd(&Yf[rl2 * YF_STRIDE + 64 + lane], v2 * xb2);
            atomicAdd(&Yf[rl3 * YF_STRIDE + lane],      v3 * xa3);
            atomicAdd(&Yf[rl3 * YF_STRIDE + 64 + lane], v3 * xb3);
        }
        for (; e < end; e += 4) {
            uint2 p0 = es[e];
            int c0 = p0.x & 0xffff, rl0 = p0.x >> 16;
            float v0 = __uint_as_float(p0.y);
            float xa0 = X[(c0 << 7) + lane], xb0 = X[(c0 << 7) + 64 + lane];
            atomicAdd(&Yf[rl0 * YF_STRIDE + lane],      v0 * xa0);
            atomicAdd(&Yf[rl0 * YF_STRIDE + 64 + lane], v0 * xb0);
        }
        __syncthreads();

        // MFMA phase: out_tile += Y * W_r
#pragma unroll
        for (int c = 0; c < 4; ++c) {
            const float* yp = &Yf[(wave * 16 + m) * YF_STRIDE + c * 32 + half * 8];
            float4 ya = *(const float4*)yp;
            float4 yb = *(const float4*)(yp + 4);
            union { uint32 u[4]; short8 s; } uu;
            uu.u[0] = pack_bf16(ya.x, ya.y);
            uu.u[1] = pack_bf16(ya.z, ya.w);
            uu.u[2] = pack_bf16(yb.x, yb.y);
            uu.u[3] = pack_bf16(yb.z, yb.w);
            short8 af = uu.s;
#pragma unroll
            for (int t = 0; t < 8; ++t) {
                short8 bf = *(const short8*)&Wt_lds[(t * 16 + m) * WT_STRIDE + c * 32 + half * 8];
                acc[t] = __builtin_amdgcn_mfma_f32_16x16x32_bf16(af, bf, acc[t], 0, 0, 0);
            }
        }
    }

    // epilogue: C/D layout col = t*16 + m, row = half*4 + reg
#pragma unroll
    for (int t = 0; t < 8; ++t) {
#pragma unroll
        for (int reg = 0; reg < 4; ++reg) {
            int grow = blk * 64 + wave * 16 + half * 4 + reg;
            if (grow < NN)
                out[(size_t)grow * DOUT + t * 16 + m] = acc[t][reg];
        }
    }
}

// ---------------------------------------------------------------------------
extern "C" void kernel_launch(void* const* d_in, const int* in_sizes, int n_in,
                              void* d_out, int out_size, void* d_ws, size_t ws_size,
                              hipStream_t stream) {
    const float* X      = (const float*)d_in[0];
    const int*   A_rows = (const int*)d_in[1];
    const int*   A_cols = (const int*)d_in[2];
    const float* A_vals = (const float*)d_in[3];
    const float* basis  = (const float*)d_in[4];
    const float* comp   = (const float*)d_in[5];
    float* out = (float*)d_out;

    char* ws = (char*)d_ws;
    ushort16* Wt         = (ushort16*)(ws + 0);          // 512 KB
    int*      counts     = (int*)(ws + 524288);          // NKEY ints (50048 B)
    int*      row_start  = (int*)(ws + 576512);          // NKEY ints
    int*      block_sums = (int*)(ws + 628736);          // 256 ints
    int*      block_offs = (int*)(ws + 629760);          // 256 ints
    uint2*    es         = (uint2*)(ws + 630784);        // 12.8 MB

    hipMemsetAsync(counts, 0, NKEY * sizeof(int), stream);

    build_wt_kernel<<<(RR * DOUT * DIN) / 256, 256, 0, stream>>>(basis, comp, Wt);

    hist_kernel<<<NNZ_C / 256, 256, 0, stream>>>(A_rows, A_cols, counts);
    scan1_kernel<<<NB2, 256, 0, stream>>>(counts, row_start, block_sums);
    scan2_kernel<<<1, 256, 0, stream>>>(block_sums, block_offs);
    scan3_kernel<<<NB2, 256, 0, stream>>>(row_start, block_offs);
    bucket_kernel<<<NNZ_C / 256, 256, 0, stream>>>(A_rows, A_cols, A_vals,
                                                   row_start, es);

    fused_spmm_kernel<<<NBLK, 256, 0, stream>>>(es, row_start, X, Wt, out);
}

// Round 4
// 417.565 us; speedup vs baseline: 4.0375x; 4.0375x over previous
//
#include <hip/hip_runtime.h>

typedef unsigned int   uint32;
typedef unsigned short ushort16;

#define NN      50000
#define RR      16
#define BB      8
#define DIN     128
#define DOUT    128
#define NNZ_C   1600000
#define NB_SCAN 196                // ceil(NN/256)

#define WT_STRIDE 136              // 128 + 8 pad (bf16 elems)

typedef short  short8  __attribute__((ext_vector_type(8)));
typedef float  floatx4 __attribute__((ext_vector_type(4)));

__device__ __forceinline__ ushort16 f2bf(float f) {
    uint32 u = __float_as_uint(f);
    u += 0x7fffu + ((u >> 16) & 1u);   // RNE
    return (ushort16)(u >> 16);
}

__device__ __forceinline__ float bf2f(ushort16 h) {
    return __uint_as_float(((uint32)h) << 16);
}

// pack two f32 -> (bf16(b)<<16)|bf16(a), round-half-up, 3 VALU ops
__device__ __forceinline__ uint32 pack_bf16(float a, float b) {
    uint32 ua = __float_as_uint(a) + 0x8000u;
    uint32 ub = __float_as_uint(b) + 0x8000u;
    return __builtin_amdgcn_perm(ub, ua, 0x07060302);
}

// ---------------------------------------------------------------------------
// Wt[r][j][k] = sum_b comp[r][b] * basis[b][k][j]   (bf16, k-contiguous)
// ---------------------------------------------------------------------------
__global__ void build_wt_kernel(const float* __restrict__ basis,
                                const float* __restrict__ comp,
                                ushort16* __restrict__ Wt) {
    int idx = blockIdx.x * 256 + threadIdx.x;      // R*DOUT*DIN = 262144
    int r = idx >> 14;
    int j = (idx >> 7) & 127;
    int k = idx & 127;
    float s = 0.f;
#pragma unroll
    for (int b = 0; b < BB; ++b)
        s += comp[r * BB + b] * basis[((size_t)b * DIN + k) * DOUT + j];
    Wt[idx] = f2bf(s);
}

// ---------------------------------------------------------------------------
// GEMM: one block = 64 X-rows x ALL 16 relations. A-frags built once in regs;
// Wt[r] staged per r (L2-resident). FW[r*N+n][j] bf16 out.
// ---------------------------------------------------------------------------
__global__ __launch_bounds__(256) void gemm_fw_kernel(
        const float* __restrict__ X,
        const ushort16* __restrict__ Wt,
        ushort16* __restrict__ FW) {
    __shared__ __align__(16) ushort16 Wt_lds[128 * WT_STRIDE];

    const int tid  = threadIdx.x;
    const int wave = tid >> 6;
    const int lane = tid & 63;
    const int m    = lane & 15;
    const int half = lane >> 4;
    const int row_base = blockIdx.x * 64 + wave * 16;

    // Build A fragments once: afrag[c] covers k = c*32 + half*8 .. +8
    short8 afrag[4];
    {
        int row  = row_base + m;
        int rowc = row < NN ? row : NN - 1;
#pragma unroll
        for (int c = 0; c < 4; ++c) {
            const float* xp = X + (size_t)rowc * DIN + c * 32 + half * 8;
            float4 xa = *(const float4*)xp;
            float4 xb = *(const float4*)(xp + 4);
            union { uint32 u[4]; short8 s; } uu;
            uu.u[0] = pack_bf16(xa.x, xa.y);
            uu.u[1] = pack_bf16(xa.z, xa.w);
            uu.u[2] = pack_bf16(xb.x, xb.y);
            uu.u[3] = pack_bf16(xb.z, xb.w);
            afrag[c] = uu.s;
        }
    }

    for (int r = 0; r < RR; ++r) {
        __syncthreads();   // protect previous iteration's LDS readers

        // stage Wt[r] into LDS (32 KB), 8 x 16B per thread
        const uint4* wt_g = (const uint4*)(Wt + (size_t)r * DOUT * DIN);
#pragma unroll
        for (int it = 0; it < 8; ++it) {
            int g8 = (it * 256 + tid) * 8;
            int j  = g8 >> 7;
            int k  = g8 & 127;
            *(uint4*)&Wt_lds[j * WT_STRIDE + k] = wt_g[g8 >> 3];
        }
        __syncthreads();

        floatx4 acc[8] = {};
#pragma unroll
        for (int c = 0; c < 4; ++c) {
#pragma unroll
            for (int t = 0; t < 8; ++t) {
                short8 bf = *(const short8*)&Wt_lds[(t * 16 + m) * WT_STRIDE + c * 32 + half * 8];
                acc[t] = __builtin_amdgcn_mfma_f32_16x16x32_bf16(afrag[c], bf, acc[t], 0, 0, 0);
            }
        }

        // epilogue: C/D layout col = t*16+m, row = half*4+reg
#pragma unroll
        for (int t = 0; t < 8; ++t) {
#pragma unroll
            for (int reg = 0; reg < 4; ++reg) {
                int grow = row_base + half * 4 + reg;
                if (grow < NN)
                    FW[((size_t)r * NN + grow) * DOUT + t * 16 + m] = f2bf(acc[t][reg]);
            }
        }
    }
}

// ---------------------------------------------------------------------------
// CSR build over rows: histogram -> scan -> cursorless bucket
// ---------------------------------------------------------------------------
__global__ void hist_kernel(const int* __restrict__ rows,
                            int* __restrict__ counts) {
    int e = blockIdx.x * 256 + threadIdx.x;
    atomicAdd(&counts[rows[e]], 1);
}

__global__ void scan1_kernel(const int* __restrict__ counts,
                             int* __restrict__ row_start,
                             int* __restrict__ block_sums) {
    __shared__ int tmp[256];
    int tid = threadIdx.x;
    int gid = blockIdx.x * 256 + tid;
    int v = (gid < NN) ? counts[gid] : 0;
    tmp[tid] = v;
    __syncthreads();
#pragma unroll
    for (int off = 1; off < 256; off <<= 1) {
        int t = (tid >= off) ? tmp[tid - off] : 0;
        __syncthreads();
        tmp[tid] += t;
        __syncthreads();
    }
    if (gid < NN) row_start[gid] = tmp[tid] - v;     // exclusive
    if (tid == 255) block_sums[blockIdx.x] = tmp[255];
}

__global__ void scan2_kernel(const int* __restrict__ block_sums,
                             int* __restrict__ block_offs) {
    __shared__ int tmp[256];
    int tid = threadIdx.x;
    int v = (tid < NB_SCAN) ? block_sums[tid] : 0;
    tmp[tid] = v;
    __syncthreads();
#pragma unroll
    for (int off = 1; off < 256; off <<= 1) {
        int t = (tid >= off) ? tmp[tid - off] : 0;
        __syncthreads();
        tmp[tid] += t;
        __syncthreads();
    }
    if (tid < NB_SCAN) block_offs[tid] = tmp[tid] - v;
}

__global__ void scan3_kernel(int* __restrict__ row_start,
                             const int* __restrict__ block_offs) {
    int gid = blockIdx.x * 256 + threadIdx.x;
    if (gid < NN) row_start[gid] += block_offs[blockIdx.x];
}

// cursorless: row_start[row] is bumped to row end; start(row) = end(row-1)
__global__ void bucket_kernel(const int* __restrict__ rows,
                              const int* __restrict__ cols,
                              const float* __restrict__ vals,
                              int* __restrict__ row_start,
                              uint2* __restrict__ es) {
    int e = blockIdx.x * 256 + threadIdx.x;
    int row = rows[e];
    int pos = atomicAdd(&row_start[row], 1);
    es[pos] = make_uint2((uint32)cols[e], __float_as_uint(vals[e]));
}

// ---------------------------------------------------------------------------
// Row accumulate: one wave per row; 4-deep software-pipelined edge loop.
// ---------------------------------------------------------------------------
__global__ __launch_bounds__(256) void row_accum_kernel(
        const uint2* __restrict__ es,
        const int* __restrict__ row_start,
        const ushort16* __restrict__ FW,
        float* __restrict__ out) {
    int row  = (blockIdx.x * 256 + threadIdx.x) >> 6;
    int lane = threadIdx.x & 63;
    if (row >= NN) return;

    int beg = (row == 0) ? 0 : row_start[row - 1];
    int end = row_start[row];

    float a0 = 0.f, a1 = 0.f;
    int e = beg;
    uint2 p0, p1, p2, p3;
    if (e + 3 < end) { p0 = es[e]; p1 = es[e+1]; p2 = es[e+2]; p3 = es[e+3]; }

    while (e + 7 < end) {
        uint2 q0 = es[e+4], q1 = es[e+5], q2 = es[e+6], q3 = es[e+7];
        uint32 f0 = *(const uint32*)(FW + (size_t)p0.x * DOUT + lane * 2);
        uint32 f1 = *(const uint32*)(FW + (size_t)p1.x * DOUT + lane * 2);
        uint32 f2 = *(const uint32*)(FW + (size_t)p2.x * DOUT + lane * 2);
        uint32 f3 = *(const uint32*)(FW + (size_t)p3.x * DOUT + lane * 2);
        float v0 = __uint_as_float(p0.y), v1 = __uint_as_float(p1.y);
        float v2 = __uint_as_float(p2.y), v3 = __uint_as_float(p3.y);
        a0 += v0 * bf2f((ushort16)(f0 & 0xffffu));
        a1 += v0 * bf2f((ushort16)(f0 >> 16));
        a0 += v1 * bf2f((ushort16)(f1 & 0xffffu));
        a1 += v1 * bf2f((ushort16)(f1 >> 16));
        a0 += v2 * bf2f((ushort16)(f2 & 0xffffu));
        a1 += v2 * bf2f((ushort16)(f2 >> 16));
        a0 += v3 * bf2f((ushort16)(f3 & 0xffffu));
        a1 += v3 * bf2f((ushort16)(f3 >> 16));
        p0 = q0; p1 = q1; p2 = q2; p3 = q3;
        e += 4;
    }
    if (e + 3 < end) {      // consume the preloaded quad
        uint32 f0 = *(const uint32*)(FW + (size_t)p0.x * DOUT + lane * 2);
        uint32 f1 = *(const uint32*)(FW + (size_t)p1.x * DOUT + lane * 2);
        uint32 f2 = *(const uint32*)(FW + (size_t)p2.x * DOUT + lane * 2);
        uint32 f3 = *(const uint32*)(FW + (size_t)p3.x * DOUT + lane * 2);
        float v0 = __uint_as_float(p0.y), v1 = __uint_as_float(p1.y);
        float v2 = __uint_as_float(p2.y), v3 = __uint_as_float(p3.y);
        a0 += v0 * bf2f((ushort16)(f0 & 0xffffu));
        a1 += v0 * bf2f((ushort16)(f0 >> 16));
        a0 += v1 * bf2f((ushort16)(f1 & 0xffffu));
        a1 += v1 * bf2f((ushort16)(f1 >> 16));
        a0 += v2 * bf2f((ushort16)(f2 & 0xffffu));
        a1 += v2 * bf2f((ushort16)(f2 >> 16));
        a0 += v3 * bf2f((ushort16)(f3 & 0xffffu));
        a1 += v3 * bf2f((ushort16)(f3 >> 16));
        e += 4;
    }
    for (; e < end; ++e) {
        uint2 p = es[e];
        uint32 f = *(const uint32*)(FW + (size_t)p.x * DOUT + lane * 2);
        float v = __uint_as_float(p.y);
        a0 += v * bf2f((ushort16)(f & 0xffffu));
        a1 += v * bf2f((ushort16)(f >> 16));
    }

    *(float2*)(out + (size_t)row * DOUT + lane * 2) = make_float2(a0, a1);
}

// ---------------------------------------------------------------------------
extern "C" void kernel_launch(void* const* d_in, const int* in_sizes, int n_in,
                              void* d_out, int out_size, void* d_ws, size_t ws_size,
                              hipStream_t stream) {
    const float* X      = (const float*)d_in[0];
    const int*   A_rows = (const int*)d_in[1];
    const int*   A_cols = (const int*)d_in[2];
    const float* A_vals = (const float*)d_in[3];
    const float* basis  = (const float*)d_in[4];
    const float* comp   = (const float*)d_in[5];
    float* out = (float*)d_out;

    char* ws = (char*)d_ws;
    ushort16* Wt         = (ushort16*)(ws + 0);               //   512 KB
    ushort16* FW         = (ushort16*)(ws + 524288);          // 204.8 MB
    int*      row_start  = (int*)(ws + 205324288);            // N ints
    int*      counts     = (int*)(ws + 205529088);            // N ints
    int*      block_sums = (int*)(ws + 205733888);            // 256 ints
    int*      block_offs = (int*)(ws + 205737984);            // 256 ints
    uint2*    es         = (uint2*)(ws + 205742080);          // 12.8 MB

    hipMemsetAsync(counts, 0, NN * sizeof(int), stream);

    build_wt_kernel<<<(RR * DOUT * DIN) / 256, 256, 0, stream>>>(basis, comp, Wt);

    gemm_fw_kernel<<<(NN + 63) / 64, 256, 0, stream>>>(X, Wt, FW);

    hist_kernel<<<NNZ_C / 256, 256, 0, stream>>>(A_rows, counts);
    scan1_kernel<<<NB_SCAN, 256, 0, stream>>>(counts, row_start, block_sums);
    scan2_kernel<<<1, 256, 0, stream>>>(block_sums, block_offs);
    scan3_kernel<<<NB_SCAN, 256, 0, stream>>>(row_start, block_offs);
    bucket_kernel<<<NNZ_C / 256, 256, 0, stream>>>(A_rows, A_cols, A_vals,
                                                   row_start, es);

    row_accum_kernel<<<(NN * 64 + 255) / 256, 256, 0, stream>>>(
        es, row_start, FW, out);
}

// Round 5
// 409.825 us; speedup vs baseline: 4.1138x; 1.0189x over previous
//
#include <hip/hip_runtime.h>

typedef unsigned int   uint32;
typedef unsigned short ushort16;

#define NN       50000
#define RR       16
#define BB       8
#define DIN      128
#define DOUT     128
#define KK       2048          // R*DIN
#define NNZ_C    1600000
#define NBUCK    196           // row>>8 buckets (256 rows each)
#define EPB      4096          // edges per block in sort passes
#define NBLK_E   391           // ceil(NNZ/EPB)
#define ROWSPLIT 25024         // phase boundary (multiple of 64)

#define WL_STRIDE 136          // 128 + 8 pad (bf16 elems)

typedef short  short8  __attribute__((ext_vector_type(8)));
typedef float  floatx4 __attribute__((ext_vector_type(4)));

__device__ __forceinline__ ushort16 f2bf(float f) {
    uint32 u = __float_as_uint(f);
    u += 0x7fffu + ((u >> 16) & 1u);   // RNE
    return (ushort16)(u >> 16);
}

__device__ __forceinline__ float bf2f(ushort16 h) {
    return __uint_as_float(((uint32)h) << 16);
}

// pack two f32 -> (bf16(b)<<16)|bf16(a), round-half-up
__device__ __forceinline__ uint32 pack_bf16(float a, float b) {
    uint32 ua = __float_as_uint(a) + 0x8000u;
    uint32 ub = __float_as_uint(b) + 0x8000u;
    return __builtin_amdgcn_perm(ub, ua, 0x07060302);
}

// ---------------------------------------------------------------------------
// Wst[jout][r*128+jin] = sum_b comp[r][b] * basis[b][jin][jout]  (bf16,
// rk-contiguous so GEMM B-fragments are contiguous loads)
// ---------------------------------------------------------------------------
__global__ void build_wst_kernel(const float* __restrict__ basis,
                                 const float* __restrict__ comp,
                                 ushort16* __restrict__ Wst) {
    int idx  = blockIdx.x * 256 + threadIdx.x;   // 128*2048 = 262144
    int jout = idx >> 11;
    int rk   = idx & 2047;
    int r    = rk >> 7;
    int jin  = rk & 127;
    float s = 0.f;
#pragma unroll
    for (int b = 0; b < BB; ++b)
        s += comp[r * BB + b] * basis[((size_t)b * DIN + jin) * DOUT + jout];
    Wst[idx] = f2bf(s);
}

// ---------------------------------------------------------------------------
// X (f32, N x 128) -> Xb (bf16 packed dwords, N x 64 dwords)
// ---------------------------------------------------------------------------
__global__ void cvt_x_kernel(const float* __restrict__ X,
                             uint32* __restrict__ XD) {
    int d = blockIdx.x * 256 + threadIdx.x;      // 3,200,000 dwords
    float2 f = *(const float2*)(X + (size_t)d * 2);
    XD[d] = pack_bf16(f.x, f.y);
}

// ---------------------------------------------------------------------------
// Sort pass 1: global bucket histogram (LDS-aggregated)
// ---------------------------------------------------------------------------
__global__ void histB_kernel(const int* __restrict__ rows,
                             int* __restrict__ counts) {
    __shared__ int h[NBUCK];
    int tid = threadIdx.x;
    if (tid < NBUCK) h[tid] = 0;
    __syncthreads();
    int base_e = blockIdx.x * EPB;
#pragma unroll
    for (int it = 0; it < 16; ++it) {
        int e = base_e + it * 256 + tid;
        if (e < NNZ_C) atomicAdd(&h[rows[e] >> 8], 1);
    }
    __syncthreads();
    if (tid < NBUCK && h[tid]) atomicAdd(&counts[tid], h[tid]);
}

// ---------------------------------------------------------------------------
// Sort pass 2: scan 196 bucket counts (single block); init cursors
// ---------------------------------------------------------------------------
__global__ void scanB_kernel(const int* __restrict__ counts,
                             int* __restrict__ bucket_start,
                             int* __restrict__ cursor) {
    __shared__ int tmp[256];
    int tid = threadIdx.x;
    int v = (tid < NBUCK) ? counts[tid] : 0;
    tmp[tid] = v;
    __syncthreads();
#pragma unroll
    for (int off = 1; off < 256; off <<= 1) {
        int t = (tid >= off) ? tmp[tid - off] : 0;
        __syncthreads();
        tmp[tid] += t;
        __syncthreads();
    }
    if (tid < NBUCK) {
        bucket_start[tid + 1] = tmp[tid];          // inclusive
        cursor[tid] = tmp[tid] - v;                // exclusive
        if (tid == 0) bucket_start[0] = 0;
    }
}

// ---------------------------------------------------------------------------
// Sort pass 3: per-block range reservation + scatter into bucket-grouped es2.
// payload x = c(16b) | kl(12b)<<16, kl = (row&255)*16 + r ; y = val bits
// ---------------------------------------------------------------------------
__global__ __launch_bounds__(256) void scatterB_kernel(
        const int* __restrict__ rows,
        const int* __restrict__ cols,
        const float* __restrict__ vals,
        int* __restrict__ cursor,
        uint2* __restrict__ es2) {
    __shared__ int h[NBUCK], gbase[NBUCK], lcur[NBUCK];
    int tid = threadIdx.x;
    if (tid < NBUCK) { h[tid] = 0; lcur[tid] = 0; }
    __syncthreads();

    int    rowv[16];
    uint32 pkx[16];
    float  vv[16];
    int base_e = blockIdx.x * EPB;
#pragma unroll
    for (int it = 0; it < 16; ++it) {
        int e = base_e + it * 256 + tid;
        if (e < NNZ_C) {
            int row = rows[e];
            int col = cols[e];
            int r   = (int)((uint32)col / (uint32)NN);
            int c   = col - r * NN;
            rowv[it] = row;
            pkx[it]  = (uint32)c | ((uint32)(((row & 255) << 4) | r) << 16);
            vv[it]   = vals[e];
            atomicAdd(&h[row >> 8], 1);
        } else rowv[it] = -1;
    }
    __syncthreads();
    if (tid < NBUCK && h[tid] > 0)
        gbase[tid] = atomicAdd(&cursor[tid], h[tid]);
    __syncthreads();
#pragma unroll
    for (int it = 0; it < 16; ++it) {
        if (rowv[it] >= 0) {
            int b   = rowv[it] >> 8;
            int pos = gbase[b] + atomicAdd(&lcur[b], 1);
            es2[pos] = make_uint2(pkx[it], __float_as_uint(vv[it]));
        }
    }
}

// ---------------------------------------------------------------------------
// Sort pass 4: one block per bucket — LDS counting-sort by sub-key
// kl = (row&255)*16 + r ; writes final es (x = c, y = val) and
// ks[row*16 + r] = global segment start (ks index algebra: b*4096 + kl).
// ---------------------------------------------------------------------------
__global__ __launch_bounds__(256) void sortB_kernel(
        const uint2* __restrict__ es2,
        const int* __restrict__ bucket_start,
        uint2* __restrict__ es,
        int* __restrict__ ks) {
    __shared__ int h[4096];
    __shared__ int cur[4096];
    __shared__ int tmp[256];
    int b    = blockIdx.x;
    int tid  = threadIdx.x;
    int base = bucket_start[b];
    int n    = bucket_start[b + 1] - base;

#pragma unroll
    for (int j = 0; j < 16; ++j) h[j * 256 + tid] = 0;
    __syncthreads();
    for (int i = tid; i < n; i += 256) {
        uint2 p = es2[base + i];
        atomicAdd(&h[(p.x >> 16) & 0xfffu], 1);
    }
    __syncthreads();

    // block-wide exclusive scan over 4096 counters
    int run = 0;
    int loc[16];
#pragma unroll
    for (int j = 0; j < 16; ++j) {
        int c = h[tid * 16 + j];
        loc[j] = run;
        run += c;
    }
    tmp[tid] = run;
    __syncthreads();
#pragma unroll
    for (int off = 1; off < 256; off <<= 1) {
        int t = (tid >= off) ? tmp[tid - off] : 0;
        __syncthreads();
        tmp[tid] += t;
        __syncthreads();
    }
    int excl_t = tmp[tid] - run;
#pragma unroll
    for (int j = 0; j < 16; ++j) {
        int idx = tid * 16 + j;
        int st  = loc[j] + excl_t;
        cur[idx] = st;
        ks[b * 4096 + idx] = base + st;
    }
    __syncthreads();

    for (int i = tid; i < n; i += 256) {
        uint2 p  = es2[base + i];
        int   kl = (p.x >> 16) & 0xfffu;
        int  pos = atomicAdd(&cur[kl], 1);
        es[base + pos] = make_uint2(p.x & 0xffffu, p.y);
    }
}

// ---------------------------------------------------------------------------
// Yc build: one wave per row. Walk the row's (row,r)-sorted edges 4-deep
// pipelined, gathering bf16 X rows (cache-resident); flush one bf16 Yc
// slice per r (zeros for empty segments). YD is dword view of Yc half.
// ---------------------------------------------------------------------------
__global__ __launch_bounds__(256) void yc_build_kernel(
        const uint2* __restrict__ es,
        const int* __restrict__ ks,
        const uint32* __restrict__ XD,
        uint32* __restrict__ YD,
        int row0, int row_end) {
    int wid = blockIdx.x * 4 + (threadIdx.x >> 6);
    int row = row0 + wid;
    if (row >= row_end) return;
    int lane = threadIdx.x & 63;

    int s = (lane < 17) ? ks[row * 16 + lane] : 0;
    int beg     = __shfl(s, 0);
    int end_row = __shfl(s, 16);

    size_t yb = (size_t)(row - row0) * 1024;   // dwords per row = 2048 bf16
    float a0 = 0.f, a1 = 0.f;
    int r_cur = 0;
    int nxt = __shfl(s, 1);

    uint2 p0 = (beg + 0 < end_row) ? es[beg + 0] : make_uint2(0u, 0u);
    uint2 p1 = (beg + 1 < end_row) ? es[beg + 1] : make_uint2(0u, 0u);
    uint2 p2 = (beg + 2 < end_row) ? es[beg + 2] : make_uint2(0u, 0u);
    uint2 p3 = (beg + 3 < end_row) ? es[beg + 3] : make_uint2(0u, 0u);

#define CONSUME(P, XV, IDX)                                               \
    { int idx_ = (IDX);                                                   \
      while (idx_ >= nxt && r_cur < 16) {                                 \
          YD[yb + r_cur * 64 + lane] = pack_bf16(a0, a1);                 \
          a0 = a1 = 0.f; r_cur++;                                         \
          nxt = (r_cur < 16) ? __shfl(s, r_cur + 1) : 0x7fffffff;         \
      }                                                                   \
      if (idx_ < end_row) {                                               \
          float v_ = __uint_as_float((P).y);                              \
          a0 += v_ * bf2f((ushort16)((XV) & 0xffffu));                    \
          a1 += v_ * bf2f((ushort16)((XV) >> 16));                        \
      } }

    for (int e = beg; e < end_row; e += 4) {
        uint2 n0 = (e + 4 < end_row) ? es[e + 4] : make_uint2(0u, 0u);
        uint2 n1 = (e + 5 < end_row) ? es[e + 5] : make_uint2(0u, 0u);
        uint2 n2 = (e + 6 < end_row) ? es[e + 6] : make_uint2(0u, 0u);
        uint2 n3 = (e + 7 < end_row) ? es[e + 7] : make_uint2(0u, 0u);
        uint32 x0 = XD[((p0.x & 0xffffu) << 6) + lane];
        uint32 x1 = XD[((p1.x & 0xffffu) << 6) + lane];
        uint32 x2 = XD[((p2.x & 0xffffu) << 6) + lane];
        uint32 x3 = XD[((p3.x & 0xffffu) << 6) + lane];
        CONSUME(p0, x0, e + 0)
        CONSUME(p1, x1, e + 1)
        CONSUME(p2, x2, e + 2)
        CONSUME(p3, x3, e + 3)
        p0 = n0; p1 = n1; p2 = n2; p3 = n3;
    }
    while (r_cur < 16) {
        YD[yb + r_cur * 64 + lane] = pack_bf16(a0, a1);
        a0 = a1 = 0.f;
        r_cur++;
    }
#undef CONSUME
}

// ---------------------------------------------------------------------------
// Dense GEMM: out[row0+rl, jout] = sum_rk Ych[rl, rk] * Wst[jout, rk]
// 64-row x 128-col tile per block; K=2048 in 16 LDS-staged slabs.
// ---------------------------------------------------------------------------
__global__ __launch_bounds__(256) void gemm_out_kernel(
        const ushort16* __restrict__ Ych,
        const ushort16* __restrict__ Wst,
        float* __restrict__ out,
        int row0, int rowmax) {
    __shared__ __align__(16) ushort16 Wl[128 * WL_STRIDE];

    const int tid  = threadIdx.x;
    const int wave = tid >> 6;
    const int lane = tid & 63;
    const int m    = lane & 15;
    const int half = lane >> 4;
    const int rb_local = blockIdx.x * 64 + wave * 16;
    const int nlocal   = rowmax - row0;

    floatx4 acc[8] = {};

    for (int k0 = 0; k0 < KK; k0 += 128) {
        __syncthreads();
#pragma unroll
        for (int it = 0; it < 8; ++it) {
            int g8   = (it * 256 + tid) * 8;
            int jout = g8 >> 7;
            int kk   = g8 & 127;
            *(uint4*)&Wl[jout * WL_STRIDE + kk] =
                *(const uint4*)&Wst[(size_t)jout * KK + k0 + kk];
        }
        __syncthreads();

        int rl = rb_local + m;
        if (rl >= nlocal) rl = nlocal - 1;
#pragma unroll
        for (int c = 0; c < 4; ++c) {
            short8 af = *(const short8*)&Ych[(size_t)rl * KK + k0 + c * 32 + half * 8];
#pragma unroll
            for (int t = 0; t < 8; ++t) {
                short8 bf = *(const short8*)&Wl[(t * 16 + m) * WL_STRIDE + c * 32 + half * 8];
                acc[t] = __builtin_amdgcn_mfma_f32_16x16x32_bf16(af, bf, acc[t], 0, 0, 0);
            }
        }
    }

    // C/D layout: col = t*16+m, row = half*4+reg
#pragma unroll
    for (int t = 0; t < 8; ++t) {
#pragma unroll
        for (int reg = 0; reg < 4; ++reg) {
            int grow = row0 + rb_local + half * 4 + reg;
            if (grow < rowmax)
                out[(size_t)grow * DOUT + t * 16 + m] = acc[t][reg];
        }
    }
}

// ---------------------------------------------------------------------------
extern "C" void kernel_launch(void* const* d_in, const int* in_sizes, int n_in,
                              void* d_out, int out_size, void* d_ws, size_t ws_size,
                              hipStream_t stream) {
    const float* X      = (const float*)d_in[0];
    const int*   A_rows = (const int*)d_in[1];
    const int*   A_cols = (const int*)d_in[2];
    const float* A_vals = (const float*)d_in[3];
    const float* basis  = (const float*)d_in[4];
    const float* comp   = (const float*)d_in[5];
    float* out = (float*)d_out;

    // workspace layout (peak 131.9 MB)
    char* ws = (char*)d_ws;
    ushort16* Wst          = (ushort16*)(ws + 0);            // 512 KB
    uint32*   XD           = (uint32*)(ws + 524288);         // 12.8 MB
    int*      ks           = (int*)(ws + 13324288);          // 802816 ints
    uint2*    es           = (uint2*)(ws + 16535552);        // 12.8 MB
    int*      bucket_start = (int*)(ws + 29335552);          // 197 ints
    int*      counts       = (int*)(ws + 29336576);          // 196 ints
    int*      cursor       = (int*)(ws + 29337600);          // 196 ints
    uint2*    es2          = (uint2*)(ws + 29339648);        // 12.8 MB
    ushort16* Ych          = (ushort16*)(ws + 29339648);     // 102.5 MB (reuses es2 after sortB)
    uint32*   YD           = (uint32*)Ych;

    hipMemsetAsync(counts, 0, NBUCK * sizeof(int), stream);

    build_wst_kernel<<<1024, 256, 0, stream>>>(basis, comp, Wst);
    cvt_x_kernel<<<12500, 256, 0, stream>>>(X, XD);

    histB_kernel<<<NBLK_E, 256, 0, stream>>>(A_rows, counts);
    scanB_kernel<<<1, 256, 0, stream>>>(counts, bucket_start, cursor);
    scatterB_kernel<<<NBLK_E, 256, 0, stream>>>(A_rows, A_cols, A_vals,
                                                cursor, es2);
    sortB_kernel<<<NBUCK, 256, 0, stream>>>(es2, bucket_start, es, ks);

    // phase 1: rows [0, ROWSPLIT)
    yc_build_kernel<<<ROWSPLIT / 4, 256, 0, stream>>>(es, ks, XD, YD, 0, ROWSPLIT);
    gemm_out_kernel<<<ROWSPLIT / 64, 256, 0, stream>>>(Ych, Wst, out, 0, ROWSPLIT);

    // phase 2: rows [ROWSPLIT, NN)
    int rows2 = NN - ROWSPLIT;                       // 24976, multiple of 4
    yc_build_kernel<<<rows2 / 4, 256, 0, stream>>>(es, ks, XD, YD, ROWSPLIT, NN);
    gemm_out_kernel<<<(rows2 + 63) / 64, 256, 0, stream>>>(Ych, Wst, out, ROWSPLIT, NN);
}